// Round 4
// baseline (952.733 us; speedup 1.0000x reference)
//
#include <hip/hip_runtime.h>

#define BB  256
#define TT  500
#define ENC 700
#define ENC_PAD 704   // rows 700..703 of w1t are zeros (gather padding target)
#define HID 128

// ---------------------------------------------------------------------------
// Kernel 1: transpose w1 (HID, ENC) -> w1t (ENC_PAD, HID); pad rows = 0
// ---------------------------------------------------------------------------
__global__ __launch_bounds__(128) void transpose_w1_kernel(const float* __restrict__ w1,
                                                           float* __restrict__ w1t) {
    int c = blockIdx.x;      // 0..ENC_PAD-1
    int h = threadIdx.x;     // 0..HID-1
    w1t[c * HID + h] = (c < ENC) ? w1[h * ENC + c] : 0.0f;
}

// ---------------------------------------------------------------------------
// Fused kernel: one block per b (256 blocks x 256 threads, 1 block/CU).
//   Waves 2,3 (producers): spmm4's exact ballot-compact + ordered float4
//     gather, writing h rows for chunk k+1 into double-buffered LDS.
//   Waves 0,1 (consumers): recur's exact scan/reduce/layer-2 on chunk k.
//   Producer VMEM overlaps consumer VALU (separate pipes); h never touches
//   HBM (removes 131 MB round-trip). All accumulation orders identical to
//   the previous (verified bit-exact) kernels.
//   LDS: 51.2K hbuf + 25.8K vbuf + 0.4K pbuf + 2.4K lists = 79.8 KB.
// ---------------------------------------------------------------------------
__global__ __launch_bounds__(256, 1) void fused_kernel(const float* __restrict__ x,
                                                       const float* __restrict__ w1t,
                                                       const float* __restrict__ w2,
                                                       float* __restrict__ out) {
    __shared__ float hb[2][50 * 128];     // 51.2 KB, chunk-sized h double buffer
    __shared__ float vbuf[50 * 129];      // 25.8 KB, stride 129 -> conflict-free
    __shared__ float pbuf[2][50];
    __shared__ ushort lists[8][152];      // wave-private column lists

    const int tid  = threadIdx.x;         // 0..255
    const int lane = tid & 63;
    const int wid  = tid >> 6;            // 0..3
    const int b    = blockIdx.x;
    const unsigned long long lt = (1ull << lane) - 1ull;

    const float D   = 0.95122942450071400910f;                                 // exp(-1/20)
    const float CD  = (float)(0.13591409142295226 * 0.95122942450071400910);   // (e/20)*d
    const float CRD = (float)(-0.27182818284590452 * 0.95122942450071400910);  // (-2e/20)*d

    // ---- producer: compute h rows (t0, t0+1) (chunk-local) into hb[buf] ----
    // Identical arithmetic to spmm4_kernel; destination is LDS instead of HBM.
    auto produce_pair = [&](int buf, int chunk, int t0) {
        const int half = lane >> 5;               // 0 -> row A, 1 -> row B
        const int hl   = lane & 31;               // channels 4hl..4hl+3
        const float* xrowA = x + ((size_t)b * TT + (size_t)chunk * 50 + t0) * ENC;
        const float* xrowB = xrowA + ENC;

        float xva[11], xvb[11];
        #pragma unroll
        for (int k = 0; k < 11; ++k) {
            int c = k * 64 + lane;
            xva[k] = (c < ENC) ? xrowA[c] : 0.0f;
        }
        #pragma unroll
        for (int k = 0; k < 11; ++k) {
            int c = k * 64 + lane;
            xvb[k] = (c < ENC) ? xrowB[c] : 0.0f;
        }

        int nA = 0, nB = 0;
        #pragma unroll
        for (int k = 0; k < 11; ++k) {
            bool act = (xva[k] != 0.0f);
            unsigned long long m = __ballot(act);
            if (act) {
                int pos = nA + (int)__popcll(m & lt);
                if (pos < 144) lists[2 * wid + 0][pos] = (ushort)(k * 64 + lane);
            }
            nA += (int)__popcll(m);
        }
        #pragma unroll
        for (int k = 0; k < 11; ++k) {
            bool act = (xvb[k] != 0.0f);
            unsigned long long m = __ballot(act);
            if (act) {
                int pos = nB + (int)__popcll(m & lt);
                if (pos < 144) lists[2 * wid + 1][pos] = (ushort)(k * 64 + lane);
            }
            nB += (int)__popcll(m);
        }
        nA = (nA < 144) ? nA : 144;
        nB = (nB < 144) ? nB : 144;
        int npmax = ((nA > nB ? nA : nB) + 3) & ~3;
        if (npmax < 4) npmax = 4;
        for (int p = nA + lane; p < npmax + 4; p += 64) lists[2 * wid + 0][p] = (ushort)ENC;
        for (int p = nB + lane; p < npmax + 4; p += 64) lists[2 * wid + 1][p] = (ushort)ENC;
        // wave-private lists; in-wave LDS RAW ordered by lgkmcnt

        const ushort* mylist = lists[2 * wid + half];
        const float* wb = w1t + 4 * hl;

        float a0 = 0.f, a1 = 0.f, a2 = 0.f, a3 = 0.f;
        int c0 = mylist[0], c1 = mylist[1], c2 = mylist[2], c3 = mylist[3];
        float4 p0 = *(const float4*)(wb + (size_t)c0 * HID);
        float4 p1 = *(const float4*)(wb + (size_t)c1 * HID);
        float4 p2 = *(const float4*)(wb + (size_t)c2 * HID);
        float4 p3 = *(const float4*)(wb + (size_t)c3 * HID);
        for (int j = 0; j < npmax; j += 4) {
            int d0 = mylist[j + 4], d1 = mylist[j + 5];
            int d2 = mylist[j + 6], d3 = mylist[j + 7];
            float4 q0 = *(const float4*)(wb + (size_t)d0 * HID);
            float4 q1 = *(const float4*)(wb + (size_t)d1 * HID);
            float4 q2 = *(const float4*)(wb + (size_t)d2 * HID);
            float4 q3 = *(const float4*)(wb + (size_t)d3 * HID);
            // ordered ascending-column accumulation; 4 independent channel chains
            a0 += p0.x; a1 += p0.y; a2 += p0.z; a3 += p0.w;
            a0 += p1.x; a1 += p1.y; a2 += p1.z; a3 += p1.w;
            a0 += p2.x; a1 += p2.y; a2 += p2.z; a3 += p2.w;
            a0 += p3.x; a1 += p3.y; a2 += p3.z; a3 += p3.w;
            p0 = q0; p1 = q1; p2 = q2; p3 = q3;
        }
        // write h row (chunk-local t0+half) into LDS: contiguous 512 B per half
        float4* dst = (float4*)&hb[buf][(t0 + half) * 128] + hl;
        *dst = make_float4(a0, a1, a2, a3);
    };

    const float w2v = (tid < HID) ? w2[tid] : 0.0f;

    float ap = 0.f, aq = 0.f, rp = 0.f, rq = 0.f;   // layer-1, channel = tid (<128)
    float Ap = 0.f, Aq = 0.f, Rp = 0.f, Rq = 0.f;   // layer-2, redundant on consumer lanes

    // ---- prologue: all 4 waves fill chunk 0 (rows 0..49) into hb[0] ----
    {
        const int base  = (wid == 0) ? 0 : (wid == 1) ? 14 : (wid == 2) ? 26 : 38;
        const int pairs = (wid == 0) ? 7 : 6;
        for (int it = 0; it < pairs; ++it) produce_pair(0, 0, base + 2 * it);
    }
    __syncthreads();

    for (int chunk = 0; chunk < 10; ++chunk) {
        const int cur = chunk & 1;

        if (wid >= 2) {
            // ---- producers: chunk+1 rows into hb[cur^1] ----
            if (chunk < 9) {
                const int base  = (wid == 2) ? 0 : 26;
                const int pairs = (wid == 2) ? 13 : 12;
                for (int it = 0; it < pairs; ++it)
                    produce_pair(cur ^ 1, chunk + 1, base + 2 * it);
            }
        } else {
            // ---- consumers: layer-1 scan, 50 steps (arithmetic == recur v1) ----
            const float* hrow = &hb[cur][0];
            #pragma unroll
            for (int tl = 0; tl < 50; ++tl) {
                float h_ = hrow[tl * 128 + tid];
                float y = fmaf(D, aq, CD * ap);
                aq = y;
                ap = fmaf(D, ap, h_);
                float q = fmaf(D, rq, CRD * rp);
                float u = y + q;
                float s = (u >= 1.0f) ? 1.0f : 0.0f;
                rq = q;
                rp = fmaf(D, rp, s);
                vbuf[tl * 129 + tid] = s * w2v;     // per-channel partial of o_t
            }
        }
        __syncthreads();   // hb[cur^1] complete + vbuf ready

        // ---- reduce o_t: wave0 lanes 0..49 sum ch 0..63; wave1 ch 64..127 ----
        if (tid < 50) {
            const float* row = &vbuf[tid * 129];
            float a0 = 0.f, a1 = 0.f, a2 = 0.f, a3 = 0.f;
            #pragma unroll
            for (int k = 0; k < 64; k += 4) {
                a0 += row[k]; a1 += row[k + 1]; a2 += row[k + 2]; a3 += row[k + 3];
            }
            pbuf[0][tid] = (a0 + a1) + (a2 + a3);
        } else if (tid >= 64 && tid < 114) {
            const float* row = &vbuf[(tid - 64) * 129 + 64];
            float a0 = 0.f, a1 = 0.f, a2 = 0.f, a3 = 0.f;
            #pragma unroll
            for (int k = 0; k < 64; k += 4) {
                a0 += row[k]; a1 += row[k + 1]; a2 += row[k + 2]; a3 += row[k + 3];
            }
            pbuf[1][tid - 64] = (a0 + a1) + (a2 + a3);
        }
        __syncthreads();

        // ---- consumers: layer-2, 50 serial steps (redundant on lanes) ----
        if (tid < 128) {
            float my_s2 = 0.f;
            #pragma unroll
            for (int tl = 0; tl < 50; ++tl) {
                float ot = pbuf[0][tl] + pbuf[1][tl];
                float y2 = fmaf(D, Aq, CD * Ap);
                Aq = y2;
                Ap = fmaf(D, Ap, ot);
                float q2 = fmaf(D, Rq, CRD * Rp);
                float u2 = y2 + q2;
                float s2 = (u2 >= 1.0f) ? 1.0f : 0.0f;
                Rq = q2;
                Rp = fmaf(D, Rp, s2);
                if (tl == tid) my_s2 = s2;
            }
            if (tid < 50) out[(size_t)b * TT + chunk * 50 + tid] = my_s2;
        }
        // safety: next vbuf write happens in next chunk's phase-1 (consumers
        // only), and next pbuf write only after next chunk's first barrier,
        // which every thread (incl. lagging layer-2) must reach first.
        // Producers racing ahead write hb[old cur], which consumers finished
        // reading before this chunk's first barrier.
    }
}

// ---------------------------------------------------------------------------
extern "C" void kernel_launch(void* const* d_in, const int* in_sizes, int n_in,
                              void* d_out, int out_size, void* d_ws, size_t ws_size,
                              hipStream_t stream) {
    const float* x  = (const float*)d_in[0];   // (B, T, ENC) binary fp32
    const float* w1 = (const float*)d_in[1];   // (HID, ENC)
    const float* w2 = (const float*)d_in[2];   // (1, HID)
    float* out = (float*)d_out;                // (B, T, 1)

    float* w1t = (float*)d_ws;                 // (ENC_PAD, HID) = 360 KB

    hipLaunchKernelGGL(transpose_w1_kernel, dim3(ENC_PAD), dim3(HID), 0, stream, w1, w1t);
    hipLaunchKernelGGL(fused_kernel, dim3(BB), dim3(256), 0, stream, x, w1t, w2, out);
}

// Round 5
// 706.158 us; speedup vs baseline: 1.3492x; 1.3492x over previous
//
#include <hip/hip_runtime.h>

#define BB  256
#define TT  500
#define ENC 700
#define ENC_PAD 704   // rows 700..703 of w1t are zeros (gather padding target)
#define HID 128

// ---------------------------------------------------------------------------
// Kernel 1: transpose w1 (HID, ENC) -> w1t (ENC_PAD, HID); pad rows = 0
// ---------------------------------------------------------------------------
__global__ __launch_bounds__(128) void transpose_w1_kernel(const float* __restrict__ w1,
                                                           float* __restrict__ w1t) {
    int c = blockIdx.x;      // 0..ENC_PAD-1
    int h = threadIdx.x;     // 0..HID-1
    w1t[c * HID + h] = (c < ENC) ? w1[h * ENC + c] : 0.0f;
}

// ---------------------------------------------------------------------------
// Fused kernel v2: one block per b, 1024 threads (16 waves, 1 block/CU).
//   Round-4 failure mode: 2 producer waves/CU -> gather latency-starved
//   (VALUBusy 8.8%, 4.7 us/pair vs 1.7 modeled). v2 keeps the same
//   producer/consumer overlap but with 14 PRODUCER WAVES (4 waves/SIMD):
//   serial depth per producer drops 13 -> 2 pairs/chunk and cross-wave
//   latency hiding returns. Waves 0-1 run recur's exact scan/reduce/layer-2;
//   consumer layer-2 overlaps the next chunk's produce phase.
//   All accumulation orders identical to the verified kernels -> bit-exact.
//   LDS: 51.2K hb + 25.8K vbuf + 0.4K pbuf + 9.7K lists = 87.1 KB.
// ---------------------------------------------------------------------------
__global__ __launch_bounds__(1024, 1) void fused_kernel(const float* __restrict__ x,
                                                        const float* __restrict__ w1t,
                                                        const float* __restrict__ w2,
                                                        float* __restrict__ out) {
    __shared__ float hb[2][50 * 128];     // 51.2 KB, chunk-sized h double buffer
    __shared__ float vbuf[50 * 129];      // 25.8 KB, stride 129 -> conflict-free
    __shared__ float pbuf[2][50];
    __shared__ ushort lists[32][152];     // 2 lists per wave

    const int tid  = threadIdx.x;         // 0..1023
    const int lane = tid & 63;
    const int wid  = tid >> 6;            // 0..15
    const int b    = blockIdx.x;
    const unsigned long long lt = (1ull << lane) - 1ull;

    const float D   = 0.95122942450071400910f;                                 // exp(-1/20)
    const float CD  = (float)(0.13591409142295226 * 0.95122942450071400910);   // (e/20)*d
    const float CRD = (float)(-0.27182818284590452 * 0.95122942450071400910);  // (-2e/20)*d

    // ---- producer: compute h rows (2p, 2p+1) of `chunk` into hb[buf] ----
    // Identical arithmetic to spmm4_kernel; destination is LDS instead of HBM.
    auto produce_pair = [&](int buf, int chunk, int t0) {
        const int half = lane >> 5;               // 0 -> row A, 1 -> row B
        const int hl   = lane & 31;               // channels 4hl..4hl+3
        const float* xrowA = x + ((size_t)b * TT + (size_t)chunk * 50 + t0) * ENC;
        const float* xrowB = xrowA + ENC;

        float xva[11], xvb[11];
        #pragma unroll
        for (int k = 0; k < 11; ++k) {
            int c = k * 64 + lane;
            xva[k] = (c < ENC) ? xrowA[c] : 0.0f;
        }
        #pragma unroll
        for (int k = 0; k < 11; ++k) {
            int c = k * 64 + lane;
            xvb[k] = (c < ENC) ? xrowB[c] : 0.0f;
        }

        int nA = 0, nB = 0;
        #pragma unroll
        for (int k = 0; k < 11; ++k) {
            bool act = (xva[k] != 0.0f);
            unsigned long long m = __ballot(act);
            if (act) {
                int pos = nA + (int)__popcll(m & lt);
                if (pos < 144) lists[2 * wid + 0][pos] = (ushort)(k * 64 + lane);
            }
            nA += (int)__popcll(m);
        }
        #pragma unroll
        for (int k = 0; k < 11; ++k) {
            bool act = (xvb[k] != 0.0f);
            unsigned long long m = __ballot(act);
            if (act) {
                int pos = nB + (int)__popcll(m & lt);
                if (pos < 144) lists[2 * wid + 1][pos] = (ushort)(k * 64 + lane);
            }
            nB += (int)__popcll(m);
        }
        nA = (nA < 144) ? nA : 144;
        nB = (nB < 144) ? nB : 144;
        int npmax = ((nA > nB ? nA : nB) + 3) & ~3;
        if (npmax < 4) npmax = 4;
        for (int p = nA + lane; p < npmax + 4; p += 64) lists[2 * wid + 0][p] = (ushort)ENC;
        for (int p = nB + lane; p < npmax + 4; p += 64) lists[2 * wid + 1][p] = (ushort)ENC;
        // wave-private lists; in-wave LDS RAW ordered by lgkmcnt

        const ushort* mylist = lists[2 * wid + half];
        const float* wb = w1t + 4 * hl;

        float a0 = 0.f, a1 = 0.f, a2 = 0.f, a3 = 0.f;
        int c0 = mylist[0], c1 = mylist[1], c2 = mylist[2], c3 = mylist[3];
        float4 p0 = *(const float4*)(wb + (size_t)c0 * HID);
        float4 p1 = *(const float4*)(wb + (size_t)c1 * HID);
        float4 p2 = *(const float4*)(wb + (size_t)c2 * HID);
        float4 p3 = *(const float4*)(wb + (size_t)c3 * HID);
        for (int j = 0; j < npmax; j += 4) {
            int d0 = mylist[j + 4], d1 = mylist[j + 5];
            int d2 = mylist[j + 6], d3 = mylist[j + 7];
            float4 q0 = *(const float4*)(wb + (size_t)d0 * HID);
            float4 q1 = *(const float4*)(wb + (size_t)d1 * HID);
            float4 q2 = *(const float4*)(wb + (size_t)d2 * HID);
            float4 q3 = *(const float4*)(wb + (size_t)d3 * HID);
            // ordered ascending-column accumulation; 4 independent channel chains
            a0 += p0.x; a1 += p0.y; a2 += p0.z; a3 += p0.w;
            a0 += p1.x; a1 += p1.y; a2 += p1.z; a3 += p1.w;
            a0 += p2.x; a1 += p2.y; a2 += p2.z; a3 += p2.w;
            a0 += p3.x; a1 += p3.y; a2 += p3.z; a3 += p3.w;
            p0 = q0; p1 = q1; p2 = q2; p3 = q3;
        }
        // write h row (chunk-local t0+half) into LDS: contiguous 512 B per half
        float4* dst = (float4*)&hb[buf][(t0 + half) * 128] + hl;
        *dst = make_float4(a0, a1, a2, a3);
    };

    const float w2v = (tid < HID) ? w2[tid] : 0.0f;

    float ap = 0.f, aq = 0.f, rp = 0.f, rq = 0.f;   // layer-1, channel = tid (<128)
    float Ap = 0.f, Aq = 0.f, Rp = 0.f, Rq = 0.f;   // layer-2, redundant on consumer lanes

    // ---- prologue: all 16 waves fill chunk 0 (25 pairs) into hb[0] ----
    {
        produce_pair(0, 0, 2 * wid);
        if (wid + 16 < 25) produce_pair(0, 0, 2 * (wid + 16));
    }
    __syncthreads();

    for (int chunk = 0; chunk < 10; ++chunk) {
        const int cur = chunk & 1;

        if (wid >= 2) {
            // ---- 14 producer waves: chunk+1 (25 pairs, <=2 per wave) ----
            if (chunk < 9) {
                const int pw = wid - 2;               // 0..13
                produce_pair(cur ^ 1, chunk + 1, 2 * pw);
                if (pw + 14 < 25) produce_pair(cur ^ 1, chunk + 1, 2 * (pw + 14));
            }
        } else {
            // ---- consumers: layer-1 scan, 50 steps (arithmetic == recur v1) ----
            const float* hrow = &hb[cur][0];
            #pragma unroll
            for (int tl = 0; tl < 50; ++tl) {
                float h_ = hrow[tl * 128 + tid];
                float y = fmaf(D, aq, CD * ap);
                aq = y;
                ap = fmaf(D, ap, h_);
                float q = fmaf(D, rq, CRD * rp);
                float u = y + q;
                float s = (u >= 1.0f) ? 1.0f : 0.0f;
                rq = q;
                rp = fmaf(D, rp, s);
                vbuf[tl * 129 + tid] = s * w2v;     // per-channel partial of o_t
            }
        }
        __syncthreads();   // hb[cur^1] complete + vbuf ready

        // ---- reduce o_t: wave0 lanes 0..49 sum ch 0..63; wave1 ch 64..127 ----
        if (tid < 50) {
            const float* row = &vbuf[tid * 129];
            float a0 = 0.f, a1 = 0.f, a2 = 0.f, a3 = 0.f;
            #pragma unroll
            for (int k = 0; k < 64; k += 4) {
                a0 += row[k]; a1 += row[k + 1]; a2 += row[k + 2]; a3 += row[k + 3];
            }
            pbuf[0][tid] = (a0 + a1) + (a2 + a3);
        } else if (tid >= 64 && tid < 114) {
            const float* row = &vbuf[(tid - 64) * 129 + 64];
            float a0 = 0.f, a1 = 0.f, a2 = 0.f, a3 = 0.f;
            #pragma unroll
            for (int k = 0; k < 64; k += 4) {
                a0 += row[k]; a1 += row[k + 1]; a2 += row[k + 2]; a3 += row[k + 3];
            }
            pbuf[1][tid - 64] = (a0 + a1) + (a2 + a3);
        }
        __syncthreads();

        // ---- consumers: layer-2, 50 serial steps (overlaps next produce) ----
        if (tid < 128) {
            float my_s2 = 0.f;
            #pragma unroll
            for (int tl = 0; tl < 50; ++tl) {
                float ot = pbuf[0][tl] + pbuf[1][tl];
                float y2 = fmaf(D, Aq, CD * Ap);
                Aq = y2;
                Ap = fmaf(D, Ap, ot);
                float q2 = fmaf(D, Rq, CRD * Rp);
                float u2 = y2 + q2;
                float s2 = (u2 >= 1.0f) ? 1.0f : 0.0f;
                Rq = q2;
                Rp = fmaf(D, Rp, s2);
                if (tl == tid) my_s2 = s2;
            }
            if (tid < 50) out[(size_t)b * TT + chunk * 50 + tid] = my_s2;
        }
        // safety: producers racing ahead write hb[old cur] (consumers finished
        // it before this chunk's first barrier) and their own wave-private
        // lists; pbuf is only rewritten after the NEXT chunk's first barrier,
        // which lagging layer-2 threads must reach first.
    }
}

// ---------------------------------------------------------------------------
extern "C" void kernel_launch(void* const* d_in, const int* in_sizes, int n_in,
                              void* d_out, int out_size, void* d_ws, size_t ws_size,
                              hipStream_t stream) {
    const float* x  = (const float*)d_in[0];   // (B, T, ENC) binary fp32
    const float* w1 = (const float*)d_in[1];   // (HID, ENC)
    const float* w2 = (const float*)d_in[2];   // (1, HID)
    float* out = (float*)d_out;                // (B, T, 1)

    float* w1t = (float*)d_ws;                 // (ENC_PAD, HID) = 360 KB

    hipLaunchKernelGGL(transpose_w1_kernel, dim3(ENC_PAD), dim3(HID), 0, stream, w1, w1t);
    hipLaunchKernelGGL(fused_kernel, dim3(BB), dim3(1024), 0, stream, x, w1t, w2, out);
}